// Round 7
// baseline (615.705 us; speedup 1.0000x reference)
//
#include <hip/hip_runtime.h>
#include <cstdint>
#include <cstddef>

// Problem constants
#define CIN   192
#define COUT  192
#define KCB   1024
#define HWSZ  4096            // 64*64
#define NPIX  32768           // 8*64*64
#define LOGIT_SCALE_F 13.856406460551018f

// ---------------------------------------------------------------------------
// JAX threefry2x32 (key = (0,42)), partitionable stream: bits(i) = o0 ^ o1 of
// threefry2x32((k1,k2), (0, i))  [validated rounds 1-5: argmax-exact]
// ---------------------------------------------------------------------------
__device__ __forceinline__ void threefry_0_42(uint32_t x0, uint32_t x1,
                                              uint32_t& o0, uint32_t& o1) {
  const uint32_t ks0 = 0u;
  const uint32_t ks1 = 42u;
  const uint32_t ks2 = 0x1BD11BDAu ^ 0u ^ 42u;
  x0 += ks0; x1 += ks1;
#define TFR(r) { x0 += x1; x1 = (x1 << (r)) | (x1 >> (32 - (r))); x1 ^= x0; }
  TFR(13) TFR(15) TFR(26) TFR(6)
  x0 += ks1; x1 += ks2 + 1u;
  TFR(17) TFR(29) TFR(16) TFR(24)
  x0 += ks2; x1 += ks0 + 2u;
  TFR(13) TFR(15) TFR(26) TFR(6)
  x0 += ks0; x1 += ks1 + 3u;
  TFR(17) TFR(29) TFR(16) TFR(24)
  x0 += ks1; x1 += ks2 + 4u;
  TFR(13) TFR(15) TFR(26) TFR(6)
  x0 += ks2; x1 += ks0 + 5u;
#undef TFR
  o0 = x0; o1 = x1;
}

__device__ __forceinline__ float gumbel_from_bits(uint32_t b) {
  // precise logf kept for BOTH logs (winning gumbels live at u~1); matched
  // the XLA stream exactly for 5 rounds -- do not swap for __logf.
  float u = __uint_as_float((b >> 9) | 0x3F800000u) - 1.0f;
  u = fmaxf(u, 1.17549435e-38f);
  return -logf(-logf(u));
}

// 4x4 outer-product FMA block; per-output strict sequential fmaf chain --
// accumulation order across c is EXACTLY c ascending (bit-identical policy).
#define FMA16(acc, av, bv) do { \
  acc[0][0]=fmaf(av.x,bv.x,acc[0][0]); acc[0][1]=fmaf(av.x,bv.y,acc[0][1]); \
  acc[0][2]=fmaf(av.x,bv.z,acc[0][2]); acc[0][3]=fmaf(av.x,bv.w,acc[0][3]); \
  acc[1][0]=fmaf(av.y,bv.x,acc[1][0]); acc[1][1]=fmaf(av.y,bv.y,acc[1][1]); \
  acc[1][2]=fmaf(av.y,bv.z,acc[1][2]); acc[1][3]=fmaf(av.y,bv.w,acc[1][3]); \
  acc[2][0]=fmaf(av.z,bv.x,acc[2][0]); acc[2][1]=fmaf(av.z,bv.y,acc[2][1]); \
  acc[2][2]=fmaf(av.z,bv.z,acc[2][2]); acc[2][3]=fmaf(av.z,bv.w,acc[2][3]); \
  acc[3][0]=fmaf(av.w,bv.x,acc[3][0]); acc[3][1]=fmaf(av.w,bv.y,acc[3][1]); \
  acc[3][2]=fmaf(av.w,bv.z,acc[3][2]); acc[3][3]=fmaf(av.w,bv.w,acc[3][3]); \
} while (0)

// 1x8 FMA row: acc[k] += a * {b0,b1}[k], strict per-output chain
#define FMA8(accr, a, b0, b1) do { \
  accr[0]=fmaf(a,b0.x,accr[0]); accr[1]=fmaf(a,b0.y,accr[1]); \
  accr[2]=fmaf(a,b0.z,accr[2]); accr[3]=fmaf(a,b0.w,accr[3]); \
  accr[4]=fmaf(a,b1.x,accr[4]); accr[5]=fmaf(a,b1.y,accr[5]); \
  accr[6]=fmaf(a,b1.z,accr[6]); accr[7]=fmaf(a,b1.w,accr[7]); \
} while (0)

// ---------------------------------------------------------------------------
// Kernel 1: km = codebook @ wk^T, vm = codebook @ wv^T  (unchanged from R5)
// ---------------------------------------------------------------------------
__global__ __launch_bounds__(256) void kv_kernel(
    const float* __restrict__ cb, const float* __restrict__ wk,
    const float* __restrict__ wv, float* __restrict__ km, float* __restrict__ vm) {
  __shared__ float sCb[32][68];  // cbT [c][j]
  __shared__ float sK[32][68];   // wkT [c][o]
  __shared__ float sV[32][68];   // wvT [c][o]
  const int tid = threadIdx.x;
  const int j0 = blockIdx.x * 64;
  const int o0 = blockIdx.y * 64;
  const float4* cb4 = reinterpret_cast<const float4*>(cb);
  const float4* wk4 = reinterpret_cast<const float4*>(wk);
  const float4* wv4 = reinterpret_cast<const float4*>(wv);
  const int c4 = tid & 7, rr = tid >> 3;  // f4-col (8 = 32c), row (32)
  const int tp = tid & 15, to = tid >> 4;
  float ak[4][4] = {};
  float av_[4][4] = {};

  for (int ci = 0; ci < 6; ++ci) {
    __syncthreads();  // previous chunk's readers done
    {
      const int cf = ci * 8 + c4;
#pragma unroll
      for (int pass = 0; pass < 2; ++pass) {
        const int r = rr + pass * 32;
        float4 a = cb4[(size_t)(j0 + r) * 48 + cf];
        float4 b = wk4[(size_t)(o0 + r) * 48 + cf];
        float4 c = wv4[(size_t)(o0 + r) * 48 + cf];
        sCb[4 * c4 + 0][r] = a.x; sCb[4 * c4 + 1][r] = a.y;
        sCb[4 * c4 + 2][r] = a.z; sCb[4 * c4 + 3][r] = a.w;
        sK[4 * c4 + 0][r] = b.x; sK[4 * c4 + 1][r] = b.y;
        sK[4 * c4 + 2][r] = b.z; sK[4 * c4 + 3][r] = b.w;
        sV[4 * c4 + 0][r] = c.x; sV[4 * c4 + 1][r] = c.y;
        sV[4 * c4 + 2][r] = c.z; sV[4 * c4 + 3][r] = c.w;
      }
    }
    __syncthreads();
#pragma unroll
    for (int c = 0; c < 32; ++c) {
      float4 a = *reinterpret_cast<const float4*>(&sCb[c][4 * tp]);
      float4 bk = *reinterpret_cast<const float4*>(&sK[c][4 * to]);
      float4 bv = *reinterpret_cast<const float4*>(&sV[c][4 * to]);
      FMA16(ak, a, bk);
      FMA16(av_, a, bv);
    }
  }
#pragma unroll
  for (int ii = 0; ii < 4; ++ii) {
    float4 w;
    w.x = ak[ii][0]; w.y = ak[ii][1]; w.z = ak[ii][2]; w.w = ak[ii][3];
    *reinterpret_cast<float4*>(km + (size_t)(j0 + 4 * tp + ii) * COUT + o0 + 4 * to) = w;
    float4 v;
    v.x = av_[ii][0]; v.y = av_[ii][1]; v.z = av_[ii][2]; v.w = av_[ii][3];
    *reinterpret_cast<float4*>(vm + (size_t)(j0 + 4 * tp + ii) * COUT + o0 + 4 * to) = v;
  }
}

// ---------------------------------------------------------------------------
// Kernel 2 (qlogit): phase 1 computes the 64-px q tile into aT (R5 q_kernel
// staging + FMA chain, bit-identical q); phase 2 is a pure logit GEMM
// (64px x 128j tiles, 2048 FMA-cycles per barrier pair). NO gumbel here.
// Staging discipline: barrier; load; LDS-write; barrier -- no cross-barrier
// register carries (R3 spill / R4 VGPR lessons).
// ---------------------------------------------------------------------------
__global__ __launch_bounds__(256) void qlogit_kernel(
    const float* __restrict__ latent, const float* __restrict__ wq,
    const float* __restrict__ km, const float* __restrict__ t1p,
    float* __restrict__ logit_out) {
  __shared__ __align__(16) float aT[CIN][68];      // qT [c][p]: 52.2 KB
  __shared__ __align__(16) float stg[2][32][68];   // 17.4 KB staging arena
  float* bTf = &stg[0][0][0];                      // phase-2 overlay [32][132]
#define BT(r, j) bTf[(r) * 132 + (j)]

  const int tid = threadIdx.x;
  const int p0 = blockIdx.x * 64;
  const int n = p0 >> 12, hw0 = p0 & 4095;
  const float t1 = t1p[0];
  const int tp = tid & 15, to = tid >> 4;

  // ---- Phase 1: q tile -> aT ----
  {
    const float4* lat4 =
        reinterpret_cast<const float4*>(latent + (size_t)n * (CIN * HWSZ));
    const float4* wq4 = reinterpret_cast<const float4*>(wq);
    const int hw40 = hw0 >> 2;
    const int lf = tid & 15, lr = tid >> 4;  // latent stage: f4-col (64p), row (16c)
    const int wc4 = tid & 7, wr = tid >> 3;  // wq stage: f4-col (32c), row (32o)
    for (int ot = 0; ot < 3; ++ot) {
      const int o0 = ot * 64;
      float acc[4][4] = {};
      for (int ci = 0; ci < 6; ++ci) {
        const int c0 = ci * 32;
        __syncthreads();  // previous chunk's readers done
        {
          float4 l0 = lat4[(size_t)(c0 + lr) * (HWSZ / 4) + hw40 + lf];
          float4 l1 = lat4[(size_t)(c0 + lr + 16) * (HWSZ / 4) + hw40 + lf];
          float4 w0 = wq4[(size_t)(o0 + wr) * 48 + (c0 >> 2) + wc4];
          float4 w1 = wq4[(size_t)(o0 + wr + 32) * 48 + (c0 >> 2) + wc4];
          *reinterpret_cast<float4*>(&stg[0][lr][4 * lf]) = l0;
          *reinterpret_cast<float4*>(&stg[0][lr + 16][4 * lf]) = l1;
          stg[1][4 * wc4 + 0][wr] = w0.x; stg[1][4 * wc4 + 1][wr] = w0.y;
          stg[1][4 * wc4 + 2][wr] = w0.z; stg[1][4 * wc4 + 3][wr] = w0.w;
          stg[1][4 * wc4 + 0][wr + 32] = w1.x; stg[1][4 * wc4 + 1][wr + 32] = w1.y;
          stg[1][4 * wc4 + 2][wr + 32] = w1.z; stg[1][4 * wc4 + 3][wr + 32] = w1.w;
        }
        __syncthreads();
#pragma unroll
        for (int c = 0; c < 32; ++c) {
          float4 av = *reinterpret_cast<const float4*>(&stg[0][c][4 * tp]);
          float4 bv = *reinterpret_cast<const float4*>(&stg[1][c][4 * to]);
          FMA16(acc, av, bv);
        }
      }
      // qT into aT: aT[o][p]  (readers are post-barrier in phase 2)
#pragma unroll
      for (int ii = 0; ii < 4; ++ii)
#pragma unroll
        for (int kk = 0; kk < 4; ++kk)
          aT[o0 + 4 * to + kk][4 * tp + ii] = acc[ii][kk];
    }
  }

  // ---- Phase 2: logit GEMM, j-tiles of 128, thread tile 4px x 8j ----
  const float4* km4 = reinterpret_cast<const float4*>(km);
  const int sc4 = tid & 7, sjj = tid >> 3;  // km stage: f4-col (32c), row (32j)

  for (int jt = 0; jt < 8; ++jt) {
    float acc[4][8] = {};
    for (int ci = 0; ci < 6; ++ci) {
      const int c0 = ci * 32;
      __syncthreads();  // previous readers done (covers phase-1 aT writes too)
      {
#pragma unroll
        for (int pass = 0; pass < 4; ++pass) {
          const int jloc = sjj + pass * 32;
          const int jg = jt * 128 + jloc;
          float4 v = km4[(size_t)jg * 48 + (c0 >> 2) + sc4];
          BT(4 * sc4 + 0, jloc) = v.x; BT(4 * sc4 + 1, jloc) = v.y;
          BT(4 * sc4 + 2, jloc) = v.z; BT(4 * sc4 + 3, jloc) = v.w;
        }
      }
      __syncthreads();
#pragma unroll
      for (int c = 0; c < 32; ++c) {
        float4 av = *reinterpret_cast<const float4*>(&aT[c0 + c][4 * tp]);
        float4 b0 = *reinterpret_cast<const float4*>(&BT(c, 8 * to));
        float4 b1 = *reinterpret_cast<const float4*>(&BT(c, 8 * to + 4));
        FMA8(acc[0], av.x, b0, b1);
        FMA8(acc[1], av.y, b0, b1);
        FMA8(acc[2], av.z, b0, b1);
        FMA8(acc[3], av.w, b0, b1);
      }
    }
    // epilogue: scale exactly as ref (/scale then *t1), store logit
#pragma unroll
    for (int ii = 0; ii < 4; ++ii) {
      const int p = p0 + 4 * tp + ii;
      const int jb = jt * 128 + 8 * to;
      float4 w0, w1;
      w0.x = acc[ii][0] / LOGIT_SCALE_F * t1;
      w0.y = acc[ii][1] / LOGIT_SCALE_F * t1;
      w0.z = acc[ii][2] / LOGIT_SCALE_F * t1;
      w0.w = acc[ii][3] / LOGIT_SCALE_F * t1;
      w1.x = acc[ii][4] / LOGIT_SCALE_F * t1;
      w1.y = acc[ii][5] / LOGIT_SCALE_F * t1;
      w1.z = acc[ii][6] / LOGIT_SCALE_F * t1;
      w1.w = acc[ii][7] / LOGIT_SCALE_F * t1;
      float* lrow = logit_out + (size_t)p * KCB + jb;
      *reinterpret_cast<float4*>(lrow) = w0;
      *reinterpret_cast<float4*>(lrow + 4) = w1;
    }
  }
#undef BT
}

// ---------------------------------------------------------------------------
// Kernel 3 (gumbel): stream stored logits; exact threefry/gumbel stream;
// dual argmax (trueCode on logit, sample on logit+gumbel); V-row gather.
// Block = 16 consecutive pixels (4 waves x 4 px); no LDS staging, high
// occupancy, pure VALU stream. Reduce semantics identical to rounds 2-5
// (strict > keeps smallest j in-lane; cross-lane tie -> min index).
// ---------------------------------------------------------------------------
__global__ __launch_bounds__(256) void gumbel_kernel(
    const float* __restrict__ logit, const float* __restrict__ vm,
    float* __restrict__ code_out, float* __restrict__ quant_out) {
  __shared__ int sIdx[16];
  const int tid = threadIdx.x;
  const int p0 = blockIdx.x * 16;
  const int wv = tid >> 6, lane = tid & 63;

#pragma unroll 1
  for (int k = 0; k < 4; ++k) {
    const int p = p0 + wv * 4 + k;
    const float* lrow = logit + (size_t)p * KCB;
    float Lv = -INFINITY, Sv = -INFINITY;
    int Li = 0, Si = 0;
    const uint32_t pbase = (uint32_t)p * (uint32_t)KCB;
#pragma unroll
    for (int ch = 0; ch < 4; ++ch) {
      const int jb = ch * 256 + 4 * lane;
      const float4 v = *reinterpret_cast<const float4*>(lrow + jb);
      const float vals[4] = {v.x, v.y, v.z, v.w};
#pragma unroll
      for (int jj = 0; jj < 4; ++jj) {
        const int j = jb + jj;              // ascending within lane
        const float val = vals[jj];
        if (val > Lv) { Lv = val; Li = j; }
        uint32_t b0, b1;
        threefry_0_42(0u, pbase + (uint32_t)j, b0, b1);
        const float s = val + gumbel_from_bits(b0 ^ b1);
        if (s > Sv) { Sv = s; Si = j; }
      }
    }
    // 64-lane butterfly argmax reduce, min-index tie-break
#pragma unroll
    for (int m = 1; m <= 32; m <<= 1) {
      const float v2 = __shfl_xor(Lv, m); const int i2 = __shfl_xor(Li, m);
      if (v2 > Lv || (v2 == Lv && i2 < Li)) { Lv = v2; Li = i2; }
      const float s2 = __shfl_xor(Sv, m); const int j2 = __shfl_xor(Si, m);
      if (s2 > Sv || (s2 == Sv && j2 < Si)) { Sv = s2; Si = j2; }
    }
    if (lane == 0) {
      code_out[p] = (float)Li;
      sIdx[wv * 4 + k] = Si;
    }
  }
  __syncthreads();

  // gather: quantized[n][d][hw] = vm[idx[p]][d]; 16 consecutive px per block
  // -> 64B-contiguous store segments per 16 lanes
  {
    const int px = tid & 15, d0 = tid >> 4;
    const int p = p0 + px;
    const int nn = p >> 12, hw = p & 4095;
    const int jv = sIdx[px];
    const float* vrow = vm + (size_t)jv * COUT;
    float* qb = quant_out + (size_t)nn * (COUT * HWSZ) + hw;
#pragma unroll
    for (int it = 0; it < 12; ++it) {
      const int d = it * 16 + d0;
      qb[(size_t)d * HWSZ] = vrow[d];
    }
  }
}

// ---------------------------------------------------------------------------
extern "C" void kernel_launch(void* const* d_in, const int* in_sizes, int n_in,
                              void* d_out, int out_size, void* d_ws, size_t ws_size,
                              hipStream_t stream) {
  (void)in_sizes; (void)n_in; (void)out_size; (void)ws_size;
  const float* latent   = (const float*)d_in[0];
  const float* codebook = (const float*)d_in[1];
  const float* wq       = (const float*)d_in[2];
  const float* wk       = (const float*)d_in[3];
  const float* wv       = (const float*)d_in[4];
  const float* t1       = (const float*)d_in[5];
  // d_in[6] = temperature (int, ==1): positive scalar, cannot change outputs

  float* ws = (float*)d_ws;
  float* km = ws;               // 196,608 floats
  float* vm = ws + 196608;      // 196,608 floats  (total ws use: 1.57 MB)

  float* quant = (float*)d_out;          // 6,291,456
  float* code  = quant + 6291456;        //    32,768
  float* logit = code + 32768;           // 33,554,432

  kv_kernel<<<dim3(16, 3), dim3(256), 0, stream>>>(codebook, wk, wv, km, vm);
  qlogit_kernel<<<dim3(NPIX / 64), dim3(256), 0, stream>>>(latent, wq, km, t1, logit);
  gumbel_kernel<<<dim3(NPIX / 16), dim3(256), 0, stream>>>(logit, vm, code, quant);
}

// Round 10
// 462.053 us; speedup vs baseline: 1.3325x; 1.3325x over previous
//
#include <hip/hip_runtime.h>
#include <cstdint>
#include <cstddef>

// Problem constants
#define CIN   192
#define COUT  192
#define KCB   1024
#define HWSZ  4096            // 64*64
#define NPIX  32768           // 8*64*64
#define LOGIT_SCALE_F 13.856406460551018f

// q tile is stashed in the logit region of d_out, cols [832,1024) of each
// pixel's 1024-wide row (proven rounds 2-5). Blocks only touch their own
// rows; all stash reads precede the jt=3 epilogue writes to those columns.
#define QCOL0 832

// ---------------------------------------------------------------------------
// JAX threefry2x32 (key = (0,42)), partitionable stream: bits(i) = o0 ^ o1 of
// threefry2x32((k1,k2), (0, i))  [validated rounds 1-7: argmax-exact]
// ---------------------------------------------------------------------------
__device__ __forceinline__ void threefry_0_42(uint32_t x0, uint32_t x1,
                                              uint32_t& o0, uint32_t& o1) {
  const uint32_t ks0 = 0u;
  const uint32_t ks1 = 42u;
  const uint32_t ks2 = 0x1BD11BDAu ^ 0u ^ 42u;
  x0 += ks0; x1 += ks1;
#define TFR(r) { x0 += x1; x1 = (x1 << (r)) | (x1 >> (32 - (r))); x1 ^= x0; }
  TFR(13) TFR(15) TFR(26) TFR(6)
  x0 += ks1; x1 += ks2 + 1u;
  TFR(17) TFR(29) TFR(16) TFR(24)
  x0 += ks2; x1 += ks0 + 2u;
  TFR(13) TFR(15) TFR(26) TFR(6)
  x0 += ks0; x1 += ks1 + 3u;
  TFR(17) TFR(29) TFR(16) TFR(24)
  x0 += ks1; x1 += ks2 + 4u;
  TFR(13) TFR(15) TFR(26) TFR(6)
  x0 += ks2; x1 += ks0 + 5u;
#undef TFR
  o0 = x0; o1 = x1;
}

__device__ __forceinline__ float gumbel_from_bits(uint32_t b) {
  // precise logf kept for BOTH logs (winning gumbels live at u~1); matched
  // the XLA stream exactly for 7 rounds -- do not swap for __logf.
  float u = __uint_as_float((b >> 9) | 0x3F800000u) - 1.0f;
  u = fmaxf(u, 1.17549435e-38f);
  return -logf(-logf(u));
}

// 4x4 outer-product FMA block (kv_kernel); strict per-output fmaf chain,
// c ascending (bit-identical policy).
#define FMA16(acc, av, bv) do { \
  acc[0][0]=fmaf(av.x,bv.x,acc[0][0]); acc[0][1]=fmaf(av.x,bv.y,acc[0][1]); \
  acc[0][2]=fmaf(av.x,bv.z,acc[0][2]); acc[0][3]=fmaf(av.x,bv.w,acc[0][3]); \
  acc[1][0]=fmaf(av.y,bv.x,acc[1][0]); acc[1][1]=fmaf(av.y,bv.y,acc[1][1]); \
  acc[1][2]=fmaf(av.y,bv.z,acc[1][2]); acc[1][3]=fmaf(av.y,bv.w,acc[1][3]); \
  acc[2][0]=fmaf(av.z,bv.x,acc[2][0]); acc[2][1]=fmaf(av.z,bv.y,acc[2][1]); \
  acc[2][2]=fmaf(av.z,bv.z,acc[2][2]); acc[2][3]=fmaf(av.z,bv.w,acc[2][3]); \
  acc[3][0]=fmaf(av.w,bv.x,acc[3][0]); acc[3][1]=fmaf(av.w,bv.y,acc[3][1]); \
  acc[3][2]=fmaf(av.w,bv.z,acc[3][2]); acc[3][3]=fmaf(av.w,bv.w,acc[3][3]); \
} while (0)

// ---------------------------------------------------------------------------
// Kernel 1: km = codebook @ wk^T, vm = codebook @ wv^T  (unchanged, bit-exact)
// ---------------------------------------------------------------------------
__global__ __launch_bounds__(256) void kv_kernel(
    const float* __restrict__ cb, const float* __restrict__ wk,
    const float* __restrict__ wv, float* __restrict__ km, float* __restrict__ vm) {
  __shared__ float sCb[32][68];  // cbT [c][j]
  __shared__ float sK[32][68];   // wkT [c][o]
  __shared__ float sV[32][68];   // wvT [c][o]
  const int tid = threadIdx.x;
  const int j0 = blockIdx.x * 64;
  const int o0 = blockIdx.y * 64;
  const float4* cb4 = reinterpret_cast<const float4*>(cb);
  const float4* wk4 = reinterpret_cast<const float4*>(wk);
  const float4* wv4 = reinterpret_cast<const float4*>(wv);
  const int c4 = tid & 7, rr = tid >> 3;  // f4-col (8 = 32c), row (32)
  const int tp = tid & 15, to = tid >> 4;
  float ak[4][4] = {};
  float av_[4][4] = {};

  for (int ci = 0; ci < 6; ++ci) {
    __syncthreads();  // previous chunk's readers done
    {
      const int cf = ci * 8 + c4;
#pragma unroll
      for (int pass = 0; pass < 2; ++pass) {
        const int r = rr + pass * 32;
        float4 a = cb4[(size_t)(j0 + r) * 48 + cf];
        float4 b = wk4[(size_t)(o0 + r) * 48 + cf];
        float4 c = wv4[(size_t)(o0 + r) * 48 + cf];
        sCb[4 * c4 + 0][r] = a.x; sCb[4 * c4 + 1][r] = a.y;
        sCb[4 * c4 + 2][r] = a.z; sCb[4 * c4 + 3][r] = a.w;
        sK[4 * c4 + 0][r] = b.x; sK[4 * c4 + 1][r] = b.y;
        sK[4 * c4 + 2][r] = b.z; sK[4 * c4 + 3][r] = b.w;
        sV[4 * c4 + 0][r] = c.x; sV[4 * c4 + 1][r] = c.y;
        sV[4 * c4 + 2][r] = c.z; sV[4 * c4 + 3][r] = c.w;
      }
    }
    __syncthreads();
#pragma unroll
    for (int c = 0; c < 32; ++c) {
      float4 a = *reinterpret_cast<const float4*>(&sCb[c][4 * tp]);
      float4 bk = *reinterpret_cast<const float4*>(&sK[c][4 * to]);
      float4 bv = *reinterpret_cast<const float4*>(&sV[c][4 * to]);
      FMA16(ak, a, bk);
      FMA16(av_, a, bv);
    }
  }
#pragma unroll
  for (int ii = 0; ii < 4; ++ii) {
    float4 w;
    w.x = ak[ii][0]; w.y = ak[ii][1]; w.z = ak[ii][2]; w.w = ak[ii][3];
    *reinterpret_cast<float4*>(km + (size_t)(j0 + 4 * tp + ii) * COUT + o0 + 4 * to) = w;
    float4 v;
    v.x = av_[ii][0]; v.y = av_[ii][1]; v.z = av_[ii][2]; v.w = av_[ii][3];
    *reinterpret_cast<float4*>(vm + (size_t)(j0 + 4 * tp + ii) * COUT + o0 + 4 * to) = v;
  }
}

// ---------------------------------------------------------------------------
// Kernel 2 (q): q[p][o] = sum_c latent[n][c][hw] * wq[o][c] -> stash at
// logit cols [QCOL0,QCOL0+192). Tile 32px x 192o (full N), thread 2px x 12o:
// A-frag 8B (bank-perfect), B-frag 48B wave-broadcast -> LDS-light.
// Chain strictly c-ascending => q bit-identical to rounds 1-7.
// ---------------------------------------------------------------------------
__global__ __launch_bounds__(256) void q_kernel(
    const float* __restrict__ latent, const float* __restrict__ wq,
    float* __restrict__ logitq) {
  __shared__ float sA[32][36];   // latT [c][px], 32 px
  __shared__ float sB[32][196];  // wqT  [c][o], 192 o
  const int tid = threadIdx.x;
  const int p0 = blockIdx.x * 32;
  const int n = p0 >> 12, hw0 = p0 & 4095;
  const float4* lat4 =
      reinterpret_cast<const float4*>(latent + (size_t)n * (CIN * HWSZ));
  const float4* wq4 = reinterpret_cast<const float4*>(wq);
  const int hw40 = hw0 >> 2;
  const int af = tid & 7, ar = tid >> 3;   // A stage: f4-col (8=32px), c-row (32)
  const int wc8 = tid & 7, wr = tid >> 3;  // B stage: f4-col (8=32c), o-row (32, x6)
  const int tp = tid & 15, to = tid >> 4;  // thread tile: 2px x 12o
  float acc[2][12] = {};

  for (int ci = 0; ci < 6; ++ci) {
    const int c0 = ci * 32;
    __syncthreads();  // previous chunk's readers done
    {
      // A: latent already [c][hw] -> contiguous float4 write, no transpose
      float4 l = lat4[(size_t)(c0 + ar) * (HWSZ / 4) + hw40 + af];
      *reinterpret_cast<float4*>(&sA[ar][4 * af]) = l;
      // B: wq rows -> transposed sB[c][o]
#pragma unroll
      for (int pass = 0; pass < 6; ++pass) {
        const int o = wr + pass * 32;
        float4 w = wq4[(size_t)o * 48 + (c0 >> 2) + wc8];
        sB[4 * wc8 + 0][o] = w.x; sB[4 * wc8 + 1][o] = w.y;
        sB[4 * wc8 + 2][o] = w.z; sB[4 * wc8 + 3][o] = w.w;
      }
    }
    __syncthreads();
#pragma unroll
    for (int c = 0; c < 32; ++c) {
      float2 a2 = *reinterpret_cast<const float2*>(&sA[c][2 * tp]);
      float4 b0 = *reinterpret_cast<const float4*>(&sB[c][12 * to]);
      float4 b1 = *reinterpret_cast<const float4*>(&sB[c][12 * to + 4]);
      float4 b2 = *reinterpret_cast<const float4*>(&sB[c][12 * to + 8]);
      const float av[2] = {a2.x, a2.y};
      const float bv[12] = {b0.x, b0.y, b0.z, b0.w, b1.x, b1.y,
                            b1.z, b1.w, b2.x, b2.y, b2.z, b2.w};
#pragma unroll
      for (int i = 0; i < 2; ++i)
#pragma unroll
        for (int k = 0; k < 12; ++k)
          acc[i][k] = fmaf(av[i], bv[k], acc[i][k]);
    }
  }
#pragma unroll
  for (int i = 0; i < 2; ++i) {
    const int p = p0 + 2 * tp + i;
    float* qr = logitq + (size_t)p * KCB + QCOL0 + 12 * to;
    float4 w0, w1, w2;
    w0.x = acc[i][0]; w0.y = acc[i][1]; w0.z = acc[i][2]; w0.w = acc[i][3];
    w1.x = acc[i][4]; w1.y = acc[i][5]; w1.z = acc[i][6]; w1.w = acc[i][7];
    w2.x = acc[i][8]; w2.y = acc[i][9]; w2.z = acc[i][10]; w2.w = acc[i][11];
    *reinterpret_cast<float4*>(qr) = w0;
    *reinterpret_cast<float4*>(qr + 4) = w1;
    *reinterpret_cast<float4*>(qr + 8) = w2;
  }
}

// ---------------------------------------------------------------------------
// Kernel 3 (fused): logit GEMM + gumbel + dual argmax + V gather.
// LDS-BW fix: thread tile 4px x 16j. Per c-iter per thread: A 16B (1 b128,
// conflict-free), B 64B (4 b128, wave-broadcast: 4 distinct addrs/wave)
// -> VALU becomes the binding pipe instead of LDS (rounds 2-7 were
// LDS-BW-bound at ~21% of fp32 peak with 1.0-1.25 B/FLOP tiles).
// Block = 64px x full 1024j (4 jt-subtiles of 256); A re-staged per jt from
// the q stash. Gumbel fused per jt (R5 vs R7 A/B: fusion is free).
// Numerics bit-identical: per-output fmaf chain strictly c-ascending, same
// gumbel stream, same tie-breaks.
// ---------------------------------------------------------------------------
__global__ __launch_bounds__(256, 2) void logit_kernel(
    const float* __restrict__ km, const float* __restrict__ vm,
    const float* __restrict__ t1p, float* __restrict__ logit_out,
    float* __restrict__ code_out, float* __restrict__ quant_out) {
  __shared__ float sA[32][68];    // qT chunk [c][px], 64 px: 8.5 KB
  __shared__ float sB[32][260];   // kmT chunk [c][j], 256 j: 32.5 KB
  __shared__ float wLv[64][4];
  __shared__ int   wLi[64][4];
  __shared__ float wSv[64][4];
  __shared__ int   wSi[64][4];
  __shared__ int   sIdx[64];

  const int tid = threadIdx.x;
  const int p0 = blockIdx.x * 64;
  const float t1 = t1p[0];
  const int tp = tid & 15;  // pixel frag: rows 4tp..4tp+3
  const int to = tid >> 4;  // j frag: 16to..16to+15
  const int qc8 = tid & 7, qr = tid >> 3;  // staging: f4-col, row
  const float4* km4 = reinterpret_cast<const float4*>(km);

  float Lv[4], Sv[4];
  int Li[4], Si[4];
#pragma unroll
  for (int ii = 0; ii < 4; ++ii) {
    Lv[ii] = -INFINITY; Sv[ii] = -INFINITY; Li[ii] = 0; Si[ii] = 0;
  }

  for (int jt = 0; jt < 4; ++jt) {
    float acc[4][16] = {};
    for (int ci = 0; ci < 6; ++ci) {
      const int c0 = ci * 32;
      __syncthreads();  // previous chunk's readers done
      {
        // A chunk: q rows p0..p0+63, cols c0..c0+31, transposed into sA[c][px]
#pragma unroll
        for (int pass = 0; pass < 2; ++pass) {
          const int r = qr + pass * 32;
          float4 a = *reinterpret_cast<const float4*>(
              logit_out + (size_t)(p0 + r) * KCB + QCOL0 + c0 + 4 * qc8);
          sA[4 * qc8 + 0][r] = a.x; sA[4 * qc8 + 1][r] = a.y;
          sA[4 * qc8 + 2][r] = a.z; sA[4 * qc8 + 3][r] = a.w;
        }
        // B chunk: km rows jt*256..+255, cols c0..c0+31 -> sB[c][j]
#pragma unroll
        for (int pass = 0; pass < 8; ++pass) {
          const int j = qr + pass * 32;
          float4 b = km4[(size_t)(jt * 256 + j) * 48 + (c0 >> 2) + qc8];
          sB[4 * qc8 + 0][j] = b.x; sB[4 * qc8 + 1][j] = b.y;
          sB[4 * qc8 + 2][j] = b.z; sB[4 * qc8 + 3][j] = b.w;
        }
      }
      __syncthreads();
#pragma unroll
      for (int c = 0; c < 32; ++c) {
        float4 a = *reinterpret_cast<const float4*>(&sA[c][4 * tp]);
        float4 b0 = *reinterpret_cast<const float4*>(&sB[c][16 * to]);
        float4 b1 = *reinterpret_cast<const float4*>(&sB[c][16 * to + 4]);
        float4 b2 = *reinterpret_cast<const float4*>(&sB[c][16 * to + 8]);
        float4 b3 = *reinterpret_cast<const float4*>(&sB[c][16 * to + 12]);
        const float av[4] = {a.x, a.y, a.z, a.w};
        const float bv[16] = {b0.x, b0.y, b0.z, b0.w, b1.x, b1.y, b1.z, b1.w,
                              b2.x, b2.y, b2.z, b2.w, b3.x, b3.y, b3.z, b3.w};
#pragma unroll
        for (int i = 0; i < 4; ++i)
#pragma unroll
          for (int k = 0; k < 16; ++k)
            acc[i][k] = fmaf(av[i], bv[k], acc[i][k]);
      }
    }
    // epilogue: scale exactly as ref (/scale then *t1), store logit,
    // fused gumbel + dual argmax update (exact stream, j ascending)
#pragma unroll
    for (int i = 0; i < 4; ++i) {
      const int p = p0 + 4 * tp + i;
      const int jb = jt * 256 + 16 * to;
      float lv[16];
#pragma unroll
      for (int k = 0; k < 16; ++k) lv[k] = acc[i][k] / LOGIT_SCALE_F * t1;
      float* lrow = logit_out + (size_t)p * KCB + jb;
#pragma unroll
      for (int m = 0; m < 4; ++m) {
        float4 w;
        w.x = lv[4 * m + 0]; w.y = lv[4 * m + 1];
        w.z = lv[4 * m + 2]; w.w = lv[4 * m + 3];
        *reinterpret_cast<float4*>(lrow + 4 * m) = w;
      }
      const uint32_t pb = (uint32_t)p * (uint32_t)KCB + (uint32_t)jb;
#pragma unroll
      for (int k = 0; k < 16; ++k) {
        const float val = lv[k];
        if (val > Lv[i]) { Lv[i] = val; Li[i] = jb + k; }  // j ascending
        uint32_t b0, b1;
        threefry_0_42(0u, pb + (uint32_t)k, b0, b1);
        const float s = val + gumbel_from_bits(b0 ^ b1);
        if (s > Sv[i]) { Sv[i] = s; Si[i] = jb + k; }
      }
    }
  }

  // in-wave reduce: lanes {tp, tp+16, tp+32, tp+48} share pixel rows
  {
    const int lane = tid & 63;
    const int wvid = tid >> 6;  // wave 0..3
#pragma unroll
    for (int ii = 0; ii < 4; ++ii) {
      float v = Lv[ii]; int idx = Li[ii];
      float s = Sv[ii]; int sidx = Si[ii];
#pragma unroll
      for (int m = 16; m <= 32; m <<= 1) {
        float v2 = __shfl_xor(v, m); int i2 = __shfl_xor(idx, m);
        if (v2 > v || (v2 == v && i2 < idx)) { v = v2; idx = i2; }
        float s2 = __shfl_xor(s, m); int j2 = __shfl_xor(sidx, m);
        if (s2 > s || (s2 == s && j2 < sidx)) { s = s2; sidx = j2; }
      }
      if (lane < 16) {
        const int r = 4 * tp + ii;
        wLv[r][wvid] = v; wLi[r][wvid] = idx;
        wSv[r][wvid] = s; wSi[r][wvid] = sidx;
      }
    }
  }
  __syncthreads();
  if (tid < 64) {
    const int r = tid;
    float bv = wLv[r][0]; int bi = wLi[r][0];
    float sv = wSv[r][0]; int si = wSi[r][0];
#pragma unroll
    for (int t = 1; t < 4; ++t) {
      float v1 = wLv[r][t]; int i1 = wLi[r][t];
      if (v1 > bv || (v1 == bv && i1 < bi)) { bv = v1; bi = i1; }
      float v2 = wSv[r][t]; int i2 = wSi[r][t];
      if (v2 > sv || (v2 == sv && i2 < si)) { sv = v2; si = i2; }
    }
    code_out[p0 + r] = (float)bi;
    sIdx[r] = si;
  }
  __syncthreads();

  // quantized[n][d][hw] = v[idx[p]][d]; lanes = 64 consecutive pixels
  {
    const int l = tid & 63, dg = tid >> 6;
    const int p = p0 + l;
    const int nn = p >> 12, hw = p & 4095;
    const int jv = sIdx[l];
    const float* vrow = vm + (size_t)jv * COUT;
    float* qb = quant_out + (size_t)nn * (COUT * HWSZ) + hw;
#pragma unroll
    for (int it = 0; it < 48; ++it) {
      const int d = it * 4 + dg;
      qb[(size_t)d * HWSZ] = vrow[d];
    }
  }
}

// ---------------------------------------------------------------------------
extern "C" void kernel_launch(void* const* d_in, const int* in_sizes, int n_in,
                              void* d_out, int out_size, void* d_ws, size_t ws_size,
                              hipStream_t stream) {
  (void)in_sizes; (void)n_in; (void)out_size; (void)ws_size;
  const float* latent   = (const float*)d_in[0];
  const float* codebook = (const float*)d_in[1];
  const float* wq       = (const float*)d_in[2];
  const float* wk       = (const float*)d_in[3];
  const float* wv       = (const float*)d_in[4];
  const float* t1       = (const float*)d_in[5];
  // d_in[6] = temperature (int, ==1): positive scalar, cannot change outputs

  float* ws = (float*)d_ws;
  float* km = ws;               // 196,608 floats
  float* vm = ws + 196608;      // 196,608 floats  (total ws use: 1.57 MB)

  float* quant = (float*)d_out;          // 6,291,456
  float* code  = quant + 6291456;        //    32,768
  float* logit = code + 32768;           // 33,554,432 (cols 832..1023 stage q)

  kv_kernel<<<dim3(16, 3), dim3(256), 0, stream>>>(codebook, wk, wv, km, vm);
  q_kernel<<<dim3(NPIX / 32), dim3(256), 0, stream>>>(latent, wq, logit);
  logit_kernel<<<dim3(NPIX / 64), dim3(256), 0, stream>>>(km, vm, t1, logit, code, quant);
}